// Round 1
// baseline (387.730 us; speedup 1.0000x reference)
//
#include <hip/hip_runtime.h>
#include <hip/hip_bf16.h>
#include <math.h>

// Problem constants (from reference): B=4, T=8192, D=512, S=16
#define B_ 4
#define T_ 8192
#define D_ 512
#define S_ 16

// tokens per block for attn_ts_k / out_k (32 -> 1024 blocks = 4 blocks/CU)
#define CHUNK 32

// ---------------------------------------------------------------------------
// Reduce-scatter across a wave: input vals[16] per lane (partial sums),
// output: full 64-lane sum of splat s=(lane>>2)&15, returned in every lane.
// ---------------------------------------------------------------------------
__device__ __forceinline__ float reduce_scatter16(float vals[S_], int lane) {
  {
    const int bit = (lane >> 5) & 1;
#pragma unroll
    for (int i = 0; i < 8; ++i) {
      float send = bit ? vals[i] : vals[i + 8];
      float keep = bit ? vals[i + 8] : vals[i];
      vals[i] = keep + __shfl_xor(send, 32, 64);
    }
  }
  {
    const int bit = (lane >> 4) & 1;
#pragma unroll
    for (int i = 0; i < 4; ++i) {
      float send = bit ? vals[i] : vals[i + 4];
      float keep = bit ? vals[i + 4] : vals[i];
      vals[i] = keep + __shfl_xor(send, 16, 64);
    }
  }
  {
    const int bit = (lane >> 3) & 1;
#pragma unroll
    for (int i = 0; i < 2; ++i) {
      float send = bit ? vals[i] : vals[i + 2];
      float keep = bit ? vals[i + 2] : vals[i];
      vals[i] = keep + __shfl_xor(send, 8, 64);
    }
  }
  {
    const int bit = (lane >> 2) & 1;
    float send = bit ? vals[0] : vals[1];
    float keep = bit ? vals[1] : vals[0];
    float v = keep + __shfl_xor(send, 4, 64);
    v += __shfl_xor(v, 2, 64);
    v += __shfl_xor(v, 1, 64);
    return v;
  }
}

__device__ __forceinline__ float dot4(float4 a, float4 b) {
  return a.x * b.x + a.y * b.y + a.z * b.z + a.w * b.w;
}

// ---------------------------------------------------------------------------
// Fused attn + token->splat aggregation, TWO PHASES per 32-token chunk.
// Block = 256 threads (4 waves); 1024 blocks = B * T/32 chunks.
// launch_bounds(256,4): VGPR cap 128 (measured 124 fits) -> 16 waves/CU.
//
// Phase A: wave w computes softmax for tokens t0+8w..+7, writes attn to
// global AND to a 2 KB LDS slab. No ts accumulation in registers (c_reg
// 128 VGPRs and tsa cannot co-exist).
//
// Phase B (c_reg dead): one barrier; thread owns columns d=tid and d+256;
// re-streams the chunk's x rows (L1/L2-hot from phase A) against
// LDS-broadcast attn; 32 atomicAdds into L2-resident ts.
// ---------------------------------------------------------------------------
__global__ __launch_bounds__(256, 4) void attn_ts_k(const float* __restrict__ x,
                                                    const float* __restrict__ centers,
                                                    const float* __restrict__ log_scales,
                                                    float* __restrict__ attn,
                                                    float* __restrict__ ts) {
  __shared__ __align__(16) float a_s[CHUNK][S_];  // 2 KB
  const int lane = threadIdx.x & 63;
  const int w = threadIdx.x >> 6;  // 0..3
  const int myS = (lane >> 2) & 15;
  const int b = blockIdx.x >> 8;             // 256 chunks per batch
  const int t0 = (blockIdx.x & 255) * CHUNK; // 32 tokens per block

  // ---- Phase A ----
  {
    // centers in registers (128 VGPRs)
    float4 c_reg[S_][2];
#pragma unroll
    for (int s = 0; s < S_; ++s)
#pragma unroll
      for (int j = 0; j < 2; ++j)
        c_reg[s][j] = *(const float4*)(centers + s * D_ + (j << 8) + (lane << 2));

    float c2;
    {
      float vals[S_];
#pragma unroll
      for (int s = 0; s < S_; ++s)
        vals[s] = dot4(c_reg[s][0], c_reg[s][0]) + dot4(c_reg[s][1], c_reg[s][1]);
      c2 = reduce_scatter16(vals, lane);
    }
    const float sc = fminf(fmaxf(__expf(log_scales[myS]), 0.1f), 2.0f);
    const float inv2 = 0.5f / (sc * sc);

    const int tw = t0 + (w << 3);  // this wave's 8 tokens
    const float* xr = x + ((size_t)b * T_ + tw) * D_;
    float* ar = attn + ((size_t)b * T_ + tw) * S_;

    // prefetch first token pair
    float4 na0 = *(const float4*)(xr + (lane << 2));
    float4 na1 = *(const float4*)(xr + 256 + (lane << 2));
    float4 nb0 = *(const float4*)(xr + 512 + (lane << 2));
    float4 nb1 = *(const float4*)(xr + 768 + (lane << 2));

#pragma unroll 1
    for (int tt = 0; tt < 8; tt += 2) {
      float4 a0 = na0, a1 = na1, b0 = nb0, b1 = nb1;
      if (tt + 2 < 8) {  // prefetch next pair (uniform branch)
        const float* nx = xr + (size_t)(tt + 2) * D_;
        na0 = *(const float4*)(nx + (lane << 2));
        na1 = *(const float4*)(nx + 256 + (lane << 2));
        nb0 = *(const float4*)(nx + 512 + (lane << 2));
        nb1 = *(const float4*)(nx + 768 + (lane << 2));
      }

      float x2a = dot4(a0, a0) + dot4(a1, a1);
      float x2b = dot4(b0, b0) + dot4(b1, b1);

      float va[S_], vb[S_];
#pragma unroll
      for (int s = 0; s < S_; ++s) {
        va[s] = x2a - 2.f * (dot4(a0, c_reg[s][0]) + dot4(a1, c_reg[s][1]));
        vb[s] = x2b - 2.f * (dot4(b0, c_reg[s][0]) + dot4(b1, c_reg[s][1]));
      }

      float ra = reduce_scatter16(va, lane);
      float rb = reduce_scatter16(vb, lane);
      float la = -(ra + c2) * inv2;
      float lb = -(rb + c2) * inv2;

      float ma = la, mb = lb;
      ma = fmaxf(ma, __shfl_xor(ma, 4, 64));  mb = fmaxf(mb, __shfl_xor(mb, 4, 64));
      ma = fmaxf(ma, __shfl_xor(ma, 8, 64));  mb = fmaxf(mb, __shfl_xor(mb, 8, 64));
      ma = fmaxf(ma, __shfl_xor(ma, 16, 64)); mb = fmaxf(mb, __shfl_xor(mb, 16, 64));
      ma = fmaxf(ma, __shfl_xor(ma, 32, 64)); mb = fmaxf(mb, __shfl_xor(mb, 32, 64));
      float ea = __expf(la - ma), eb = __expf(lb - mb);
      float sa = ea, sb = eb;
      sa += __shfl_xor(sa, 4, 64);  sb += __shfl_xor(sb, 4, 64);
      sa += __shfl_xor(sa, 8, 64);  sb += __shfl_xor(sb, 8, 64);
      sa += __shfl_xor(sa, 16, 64); sb += __shfl_xor(sb, 16, 64);
      sa += __shfl_xor(sa, 32, 64); sb += __shfl_xor(sb, 32, 64);
      float aa = ea / sa, ab2 = eb / sb;

      if ((lane & 3) == 0) {
        ar[(size_t)tt * S_ + myS] = aa;
        ar[(size_t)(tt + 1) * S_ + myS] = ab2;
        a_s[(w << 3) + tt][myS] = aa;
        a_s[(w << 3) + tt + 1][myS] = ab2;
      }
    }
  }  // c_reg dies here

  __syncthreads();

  // ---- Phase B ----
  {
    const int d = threadIdx.x;  // owns cols d and d+256
    float2 acc[S_];
#pragma unroll
    for (int s = 0; s < S_; ++s) acc[s] = make_float2(0.f, 0.f);

    const float* xb = x + ((size_t)b * T_ + t0) * D_;

#pragma unroll 8
    for (int t = 0; t < CHUNK; ++t) {
      float xv0 = xb[(size_t)t * D_ + d];
      float xv1 = xb[(size_t)t * D_ + d + 256];
      const float4* ap = (const float4*)a_s[t];  // LDS broadcast
      float4 q0 = ap[0], q1 = ap[1], q2 = ap[2], q3 = ap[3];
      float av[S_] = {q0.x, q0.y, q0.z, q0.w, q1.x, q1.y, q1.z, q1.w,
                      q2.x, q2.y, q2.z, q2.w, q3.x, q3.y, q3.z, q3.w};
#pragma unroll
      for (int s = 0; s < S_; ++s) {
        acc[s].x += av[s] * xv0;
        acc[s].y += av[s] * xv1;
      }
    }

    float* tb = ts + (size_t)b * S_ * D_;
#pragma unroll
    for (int s = 0; s < S_; ++s) {
      atomicAdd(tb + s * D_ + d, acc[s].x);
      atomicAdd(tb + s * D_ + d + 256, acc[s].y);
    }
  }
}

// ---------------------------------------------------------------------------
// Kernel 2 (x2): out[r,e] = sum_k in[r,k] * W[e,k]   (r = 0..63 = b*S+s)
// Split-K=4 reduced in LDS (deterministic). 512 blocks x 256 threads.
// ---------------------------------------------------------------------------
__global__ __launch_bounds__(256) void proj_k(const float* __restrict__ in,
                                              const float* __restrict__ W,
                                              float* __restrict__ out) {
  __shared__ float red[4][64];
  const int r = blockIdx.x >> 3;
  const int eb = blockIdx.x & 7;
  const int el = threadIdx.x & 63;
  const int kc = threadIdx.x >> 6;
  const int e = (eb << 6) + el;

  const float4* w4 = (const float4*)(W + (size_t)e * D_ + kc * 128);
  const float4* i4 = (const float4*)(in + (size_t)r * D_ + kc * 128);
  float acc = 0.f;
#pragma unroll
  for (int k = 0; k < 32; ++k) acc += dot4(w4[k], i4[k]);

  red[kc][el] = acc;
  __syncthreads();
  if (kc == 0)
    out[(size_t)r * D_ + e] = red[0][el] + red[1][el] + red[2][el] + red[3][el];
}

// ---------------------------------------------------------------------------
// Kernel 3: out[b,t,e] = sum_s attn[b,t,s] * ss_o[b,s,e]
// 1024 blocks x 256 threads, 32 tokens per block; 128 col-threads own 4
// contiguous cols each (float4 stores), 2 token-phases per block.
// ss_o slice in registers (16 x float4); attn wave-uniform loads.
// ---------------------------------------------------------------------------
__global__ __launch_bounds__(256, 4) void out_k(const float* __restrict__ attn,
                                                const float* __restrict__ ss_o,
                                                float* __restrict__ out) {
  const int chunks = T_ / CHUNK;  // 256
  const int b = blockIdx.x / chunks;
  const int t0 = (blockIdx.x % chunks) * CHUNK;
  const int half = threadIdx.x >> 7;   // token phase 0/1
  const int ct = threadIdx.x & 127;    // column thread
  const int e0 = ct << 2;              // 4 contiguous cols

  float4 ssf[S_];
  const float* sb = ss_o + (size_t)b * S_ * D_;
#pragma unroll
  for (int s = 0; s < S_; ++s) ssf[s] = *(const float4*)(sb + s * D_ + e0);

  const float4* ab = (const float4*)(attn + ((size_t)b * T_ + t0) * S_);
  float* ob = out + ((size_t)b * T_ + t0) * D_ + e0;

#pragma unroll 4
  for (int t = half; t < CHUNK; t += 2) {
    float4 a0 = ab[t * 4 + 0], a1 = ab[t * 4 + 1];
    float4 a2 = ab[t * 4 + 2], a3 = ab[t * 4 + 3];
    float av[S_] = {a0.x, a0.y, a0.z, a0.w, a1.x, a1.y, a1.z, a1.w,
                    a2.x, a2.y, a2.z, a2.w, a3.x, a3.y, a3.z, a3.w};
    float4 acc = make_float4(0.f, 0.f, 0.f, 0.f);
#pragma unroll
    for (int s = 0; s < S_; ++s) {
      acc.x += av[s] * ssf[s].x;
      acc.y += av[s] * ssf[s].y;
      acc.z += av[s] * ssf[s].z;
      acc.w += av[s] * ssf[s].w;
    }
    *(float4*)(ob + (size_t)t * D_) = acc;
  }
}

// ---------------------------------------------------------------------------
extern "C" void kernel_launch(void* const* d_in, const int* in_sizes, int n_in,
                              void* d_out, int out_size, void* d_ws, size_t ws_size,
                              hipStream_t stream) {
  const float* x          = (const float*)d_in[0];  // [B,T,D]
  const float* centers    = (const float*)d_in[1];  // [S,D]
  const float* log_scales = (const float*)d_in[2];  // [S]
  const float* Wv         = (const float*)d_in[3];  // [D,D]
  const float* Wo         = (const float*)d_in[4];  // [D,D]
  float* out = (float*)d_out;                       // [B,T,D]

  // workspace layout (floats): attn | ts | tmp | ss_o
  float* attn = (float*)d_ws;                        // B*T*S   = 2 MB
  float* ts   = attn + (size_t)B_ * T_ * S_;         // B*S*D   = 128 KB
  float* tmp  = ts + (size_t)B_ * S_ * D_;           // B*S*D   = 128 KB
  float* ss_o = tmp + (size_t)B_ * S_ * D_;          // B*S*D   = 128 KB

  // zero only the atomic target (tiny, L2-resident fill)
  hipMemsetAsync(ts, 0, (size_t)B_ * S_ * D_ * sizeof(float), stream);

  attn_ts_k<<<B_ * (T_ / CHUNK), 256, 0, stream>>>(x, centers, log_scales, attn, ts);
  proj_k<<<512, 256, 0, stream>>>(ts, Wv, tmp);    // tmp = ts @ Wv^T
  proj_k<<<512, 256, 0, stream>>>(tmp, Wo, ss_o);  // ss_o = tmp @ Wo^T
  out_k<<<B_ * (T_ / CHUNK), 256, 0, stream>>>(attn, ss_o, out);
}

// Round 2
// 195.228 us; speedup vs baseline: 1.9860x; 1.9860x over previous
//
#include <hip/hip_runtime.h>
#include <hip/hip_bf16.h>
#include <math.h>

// Problem constants (from reference): B=4, T=8192, D=512, S=16
#define B_ 4
#define T_ 8192
#define D_ 512
#define S_ 16

// tokens per block for attn_ts_k / out_k (32 -> 1024 blocks).
// NOTE R1 post-mortem: do NOT pair this with __launch_bounds__(...,4) —
// hipcc maps min_waves=4 to a 64-VGPR cap, which spills c_reg/ssf to
// scratch (hbm_bytes 82->470 MB, 2.2x regression). With (256,2) the
// allocator lands at ~124 VGPRs and the HW reaches 4 blocks/CU on its own.
#define CHUNK 32

// ---------------------------------------------------------------------------
// Reduce-scatter across a wave: input vals[16] per lane (partial sums),
// output: full 64-lane sum of splat s=(lane>>2)&15, returned in every lane.
// ---------------------------------------------------------------------------
__device__ __forceinline__ float reduce_scatter16(float vals[S_], int lane) {
  {
    const int bit = (lane >> 5) & 1;
#pragma unroll
    for (int i = 0; i < 8; ++i) {
      float send = bit ? vals[i] : vals[i + 8];
      float keep = bit ? vals[i + 8] : vals[i];
      vals[i] = keep + __shfl_xor(send, 32, 64);
    }
  }
  {
    const int bit = (lane >> 4) & 1;
#pragma unroll
    for (int i = 0; i < 4; ++i) {
      float send = bit ? vals[i] : vals[i + 4];
      float keep = bit ? vals[i + 4] : vals[i];
      vals[i] = keep + __shfl_xor(send, 16, 64);
    }
  }
  {
    const int bit = (lane >> 3) & 1;
#pragma unroll
    for (int i = 0; i < 2; ++i) {
      float send = bit ? vals[i] : vals[i + 2];
      float keep = bit ? vals[i + 2] : vals[i];
      vals[i] = keep + __shfl_xor(send, 8, 64);
    }
  }
  {
    const int bit = (lane >> 2) & 1;
    float send = bit ? vals[0] : vals[1];
    float keep = bit ? vals[1] : vals[0];
    float v = keep + __shfl_xor(send, 4, 64);
    v += __shfl_xor(v, 2, 64);
    v += __shfl_xor(v, 1, 64);
    return v;
  }
}

__device__ __forceinline__ float dot4(float4 a, float4 b) {
  return a.x * b.x + a.y * b.y + a.z * b.z + a.w * b.w;
}

// ---------------------------------------------------------------------------
// Fused attn + token->splat aggregation, TWO PHASES per 32-token chunk.
// Block = 256 threads (4 waves); 1024 blocks = B * T/32 chunks.
// __launch_bounds__(256,2): allocator lands ~124 VGPRs (measured R0); at
// <=128 regs HW runs 4 waves/SIMD = 4 blocks/CU with the 1024-block grid.
//
// Phase A: wave w computes softmax for tokens t0+8w..+7, writes attn to
// global AND to a 2 KB LDS slab. No ts accumulation in registers (c_reg
// 128 VGPRs and tsa cannot co-exist).
//
// Phase B (c_reg dead): one barrier; thread owns columns d=tid and d+256;
// re-streams the chunk's x rows (L1/L2-hot from phase A) against
// LDS-broadcast attn; 32 atomicAdds into L2-resident ts.
// ---------------------------------------------------------------------------
__global__ __launch_bounds__(256, 2) void attn_ts_k(const float* __restrict__ x,
                                                    const float* __restrict__ centers,
                                                    const float* __restrict__ log_scales,
                                                    float* __restrict__ attn,
                                                    float* __restrict__ ts) {
  __shared__ __align__(16) float a_s[CHUNK][S_];  // 2 KB
  const int lane = threadIdx.x & 63;
  const int w = threadIdx.x >> 6;  // 0..3
  const int myS = (lane >> 2) & 15;
  const int b = blockIdx.x >> 8;             // 256 chunks per batch
  const int t0 = (blockIdx.x & 255) * CHUNK; // 32 tokens per block

  // ---- Phase A ----
  {
    // centers in registers (128 VGPRs)
    float4 c_reg[S_][2];
#pragma unroll
    for (int s = 0; s < S_; ++s)
#pragma unroll
      for (int j = 0; j < 2; ++j)
        c_reg[s][j] = *(const float4*)(centers + s * D_ + (j << 8) + (lane << 2));

    float c2;
    {
      float vals[S_];
#pragma unroll
      for (int s = 0; s < S_; ++s)
        vals[s] = dot4(c_reg[s][0], c_reg[s][0]) + dot4(c_reg[s][1], c_reg[s][1]);
      c2 = reduce_scatter16(vals, lane);
    }
    const float sc = fminf(fmaxf(__expf(log_scales[myS]), 0.1f), 2.0f);
    const float inv2 = 0.5f / (sc * sc);

    const int tw = t0 + (w << 3);  // this wave's 8 tokens
    const float* xr = x + ((size_t)b * T_ + tw) * D_;
    float* ar = attn + ((size_t)b * T_ + tw) * S_;

    // prefetch first token pair
    float4 na0 = *(const float4*)(xr + (lane << 2));
    float4 na1 = *(const float4*)(xr + 256 + (lane << 2));
    float4 nb0 = *(const float4*)(xr + 512 + (lane << 2));
    float4 nb1 = *(const float4*)(xr + 768 + (lane << 2));

#pragma unroll 1
    for (int tt = 0; tt < 8; tt += 2) {
      float4 a0 = na0, a1 = na1, b0 = nb0, b1 = nb1;
      if (tt + 2 < 8) {  // prefetch next pair (uniform branch)
        const float* nx = xr + (size_t)(tt + 2) * D_;
        na0 = *(const float4*)(nx + (lane << 2));
        na1 = *(const float4*)(nx + 256 + (lane << 2));
        nb0 = *(const float4*)(nx + 512 + (lane << 2));
        nb1 = *(const float4*)(nx + 768 + (lane << 2));
      }

      float x2a = dot4(a0, a0) + dot4(a1, a1);
      float x2b = dot4(b0, b0) + dot4(b1, b1);

      float va[S_], vb[S_];
#pragma unroll
      for (int s = 0; s < S_; ++s) {
        va[s] = x2a - 2.f * (dot4(a0, c_reg[s][0]) + dot4(a1, c_reg[s][1]));
        vb[s] = x2b - 2.f * (dot4(b0, c_reg[s][0]) + dot4(b1, c_reg[s][1]));
      }

      float ra = reduce_scatter16(va, lane);
      float rb = reduce_scatter16(vb, lane);
      float la = -(ra + c2) * inv2;
      float lb = -(rb + c2) * inv2;

      float ma = la, mb = lb;
      ma = fmaxf(ma, __shfl_xor(ma, 4, 64));  mb = fmaxf(mb, __shfl_xor(mb, 4, 64));
      ma = fmaxf(ma, __shfl_xor(ma, 8, 64));  mb = fmaxf(mb, __shfl_xor(mb, 8, 64));
      ma = fmaxf(ma, __shfl_xor(ma, 16, 64)); mb = fmaxf(mb, __shfl_xor(mb, 16, 64));
      ma = fmaxf(ma, __shfl_xor(ma, 32, 64)); mb = fmaxf(mb, __shfl_xor(mb, 32, 64));
      float ea = __expf(la - ma), eb = __expf(lb - mb);
      float sa = ea, sb = eb;
      sa += __shfl_xor(sa, 4, 64);  sb += __shfl_xor(sb, 4, 64);
      sa += __shfl_xor(sa, 8, 64);  sb += __shfl_xor(sb, 8, 64);
      sa += __shfl_xor(sa, 16, 64); sb += __shfl_xor(sb, 16, 64);
      sa += __shfl_xor(sa, 32, 64); sb += __shfl_xor(sb, 32, 64);
      float aa = ea / sa, ab2 = eb / sb;

      if ((lane & 3) == 0) {
        ar[(size_t)tt * S_ + myS] = aa;
        ar[(size_t)(tt + 1) * S_ + myS] = ab2;
        a_s[(w << 3) + tt][myS] = aa;
        a_s[(w << 3) + tt + 1][myS] = ab2;
      }
    }
  }  // c_reg dies here

  __syncthreads();

  // ---- Phase B ----
  {
    const int d = threadIdx.x;  // owns cols d and d+256
    float2 acc[S_];
#pragma unroll
    for (int s = 0; s < S_; ++s) acc[s] = make_float2(0.f, 0.f);

    const float* xb = x + ((size_t)b * T_ + t0) * D_;

#pragma unroll 8
    for (int t = 0; t < CHUNK; ++t) {
      float xv0 = xb[(size_t)t * D_ + d];
      float xv1 = xb[(size_t)t * D_ + d + 256];
      const float4* ap = (const float4*)a_s[t];  // LDS broadcast
      float4 q0 = ap[0], q1 = ap[1], q2 = ap[2], q3 = ap[3];
      float av[S_] = {q0.x, q0.y, q0.z, q0.w, q1.x, q1.y, q1.z, q1.w,
                      q2.x, q2.y, q2.z, q2.w, q3.x, q3.y, q3.z, q3.w};
#pragma unroll
      for (int s = 0; s < S_; ++s) {
        acc[s].x += av[s] * xv0;
        acc[s].y += av[s] * xv1;
      }
    }

    float* tb = ts + (size_t)b * S_ * D_;
#pragma unroll
    for (int s = 0; s < S_; ++s) {
      atomicAdd(tb + s * D_ + d, acc[s].x);
      atomicAdd(tb + s * D_ + d + 256, acc[s].y);
    }
  }
}

// ---------------------------------------------------------------------------
// Kernel 2 (x2): out[r,e] = sum_k in[r,k] * W[e,k]   (r = 0..63 = b*S+s)
// Split-K=4 reduced in LDS (deterministic). 512 blocks x 256 threads.
// ---------------------------------------------------------------------------
__global__ __launch_bounds__(256) void proj_k(const float* __restrict__ in,
                                              const float* __restrict__ W,
                                              float* __restrict__ out) {
  __shared__ float red[4][64];
  const int r = blockIdx.x >> 3;
  const int eb = blockIdx.x & 7;
  const int el = threadIdx.x & 63;
  const int kc = threadIdx.x >> 6;
  const int e = (eb << 6) + el;

  const float4* w4 = (const float4*)(W + (size_t)e * D_ + kc * 128);
  const float4* i4 = (const float4*)(in + (size_t)r * D_ + kc * 128);
  float acc = 0.f;
#pragma unroll
  for (int k = 0; k < 32; ++k) acc += dot4(w4[k], i4[k]);

  red[kc][el] = acc;
  __syncthreads();
  if (kc == 0)
    out[(size_t)r * D_ + e] = red[0][el] + red[1][el] + red[2][el] + red[3][el];
}

// ---------------------------------------------------------------------------
// Kernel 3: out[b,t,e] = sum_s attn[b,t,s] * ss_o[b,s,e]
// 1024 blocks x 256 threads, 32 tokens per block; 128 col-threads own 4
// contiguous cols each (float4 stores), 2 token-phases per block.
// ss_o slice in registers (16 x float4); attn wave-uniform loads.
// Plain __launch_bounds__(256): no min-waves hint (see R1 post-mortem —
// the hint's 64-VGPR cap spilled ssf[16] to scratch, 193 us).
// ---------------------------------------------------------------------------
__global__ __launch_bounds__(256) void out_k(const float* __restrict__ attn,
                                             const float* __restrict__ ss_o,
                                             float* __restrict__ out) {
  const int chunks = T_ / CHUNK;  // 256
  const int b = blockIdx.x / chunks;
  const int t0 = (blockIdx.x % chunks) * CHUNK;
  const int half = threadIdx.x >> 7;   // token phase 0/1
  const int ct = threadIdx.x & 127;    // column thread
  const int e0 = ct << 2;              // 4 contiguous cols

  float4 ssf[S_];
  const float* sb = ss_o + (size_t)b * S_ * D_;
#pragma unroll
  for (int s = 0; s < S_; ++s) ssf[s] = *(const float4*)(sb + s * D_ + e0);

  const float4* ab = (const float4*)(attn + ((size_t)b * T_ + t0) * S_);
  float* ob = out + ((size_t)b * T_ + t0) * D_ + e0;

#pragma unroll 4
  for (int t = half; t < CHUNK; t += 2) {
    float4 a0 = ab[t * 4 + 0], a1 = ab[t * 4 + 1];
    float4 a2 = ab[t * 4 + 2], a3 = ab[t * 4 + 3];
    float av[S_] = {a0.x, a0.y, a0.z, a0.w, a1.x, a1.y, a1.z, a1.w,
                    a2.x, a2.y, a2.z, a2.w, a3.x, a3.y, a3.z, a3.w};
    float4 acc = make_float4(0.f, 0.f, 0.f, 0.f);
#pragma unroll
    for (int s = 0; s < S_; ++s) {
      acc.x += av[s] * ssf[s].x;
      acc.y += av[s] * ssf[s].y;
      acc.z += av[s] * ssf[s].z;
      acc.w += av[s] * ssf[s].w;
    }
    *(float4*)(ob + (size_t)t * D_) = acc;
  }
}

// ---------------------------------------------------------------------------
extern "C" void kernel_launch(void* const* d_in, const int* in_sizes, int n_in,
                              void* d_out, int out_size, void* d_ws, size_t ws_size,
                              hipStream_t stream) {
  const float* x          = (const float*)d_in[0];  // [B,T,D]
  const float* centers    = (const float*)d_in[1];  // [S,D]
  const float* log_scales = (const float*)d_in[2];  // [S]
  const float* Wv         = (const float*)d_in[3];  // [D,D]
  const float* Wo         = (const float*)d_in[4];  // [D,D]
  float* out = (float*)d_out;                       // [B,T,D]

  // workspace layout (floats): attn | ts | tmp | ss_o
  float* attn = (float*)d_ws;                        // B*T*S   = 2 MB
  float* ts   = attn + (size_t)B_ * T_ * S_;         // B*S*D   = 128 KB
  float* tmp  = ts + (size_t)B_ * S_ * D_;           // B*S*D   = 128 KB
  float* ss_o = tmp + (size_t)B_ * S_ * D_;          // B*S*D   = 128 KB

  // zero only the atomic target (tiny, L2-resident fill)
  hipMemsetAsync(ts, 0, (size_t)B_ * S_ * D_ * sizeof(float), stream);

  attn_ts_k<<<B_ * (T_ / CHUNK), 256, 0, stream>>>(x, centers, log_scales, attn, ts);
  proj_k<<<512, 256, 0, stream>>>(ts, Wv, tmp);    // tmp = ts @ Wv^T
  proj_k<<<512, 256, 0, stream>>>(tmp, Wo, ss_o);  // ss_o = tmp @ Wo^T
  out_k<<<B_ * (T_ / CHUNK), 256, 0, stream>>>(attn, ss_o, out);
}